// Round 9
// baseline (148.246 us; speedup 1.0000x reference)
//
#include <hip/hip_runtime.h>
#include <hip/hip_bf16.h>

// ---------------------------------------------------------------------------
// CrossRNN: embed-gather -> 2-layer Elman RNN (relu) -> row/col cross -> dot
// B=4 R=64 C=64 S=32 V=30000 E=H=128 L=2   N = B*R*C = 16384 sequences
//
// Round-9: layer-SKEWED single-barrier step (round-8 design) with HARDENED
// phase fence. Round 8 failed absmax 0.078: raw s_barrier is NOT a memory
// scheduling fence in LLVM -- ds_reads could be scheduled between the
// lgkmcnt(0) asm and the s_barrier (reading before peers wrote = stale h).
// Fix (rule-18 pattern): lgkmcnt(0) -> sched_barrier(0) -> s_barrier ->
// sched_barrier(0). Still does NOT drain vmcnt: distance-2 T1p gather
// prefetch stays in flight across the rendezvous.
//   Per step t (ONE barrier):
//     h1_t     = relu(Wh0·h1_{t-1} + t1_t)
//     h2_{t-1} = relu(bsum + Wi1·h1_{t-1} + Wh1·h2_{t-2})
// Grid: 512 blocks x 256 thr (4 waves, M=32/wave, 32 seqs/block), (256,2):
//   124 arch-VGPR + AGPR weights, 2 blocks/CU (proven no-spill round 6).
// ---------------------------------------------------------------------------

typedef __attribute__((ext_vector_type(8))) short short8;
typedef __attribute__((ext_vector_type(4))) float f32x4;
typedef __attribute__((ext_vector_type(2))) unsigned int u32x2;
typedef __attribute__((ext_vector_type(4))) unsigned int u32x4;

#define Hd 128
#define Sd 32
#define VROWS 30000

__device__ __forceinline__ unsigned short f2b(float f) {
  __hip_bfloat16 h = __float2bfloat16(f);
  return reinterpret_cast<unsigned short&>(h);
}
__device__ __forceinline__ unsigned int pack2(float a, float b) {
  return (unsigned int)f2b(a) | ((unsigned int)f2b(b) << 16);
}
__device__ __forceinline__ float blo(unsigned int u) { return __uint_as_float(u << 16); }
__device__ __forceinline__ float bhi(unsigned int u) { return __uint_as_float(u & 0xffff0000u); }

__device__ __forceinline__ f32x4 mfma16(short8 a, short8 b, f32x4 c) {
  return __builtin_amdgcn_mfma_f32_16x16x32_bf16(a, b, c, 0, 0, 0);
}

// HARDENED phase rendezvous: drain LDS ops, pin schedule, barrier, pin again.
// Does NOT drain vmcnt -> global prefetches stay in flight.
__device__ __forceinline__ void phase_fence() {
  asm volatile("s_waitcnt lgkmcnt(0)" ::: "memory");
  __builtin_amdgcn_sched_barrier(0);
  __builtin_amdgcn_s_barrier();
  __builtin_amdgcn_sched_barrier(0);
}

// load 8 consecutive f32 (32B aligned) -> bf16 fragment
__device__ __forceinline__ short8 load_row8_bf16(const float* __restrict__ p) {
  const float4* q = reinterpret_cast<const float4*>(p);
  float4 a = q[0], b = q[1];
  short8 s;
  s[0] = (short)f2b(a.x); s[1] = (short)f2b(a.y);
  s[2] = (short)f2b(a.z); s[3] = (short)f2b(a.w);
  s[4] = (short)f2b(b.x); s[5] = (short)f2b(b.y);
  s[6] = (short)f2b(b.z); s[7] = (short)f2b(b.w);
  return s;
}

// ---------------------------------------------------------------------------
// K1: T1p (bf16, permuted, both layer-0 biases folded). 256 blocks x 256 thr;
// each wave self-converts Wih0 (L2-resident reads) and does ~2 v-tiles.
// ---------------------------------------------------------------------------
__global__ __launch_bounds__(256, 1) void k_t1p(const float* __restrict__ embed,
                                                const float* __restrict__ W_ih,
                                                const float* __restrict__ b_ih,
                                                const float* __restrict__ b_hh,
                                                unsigned int* __restrict__ T1p) {
  const int tid = threadIdx.x, lane = tid & 63, wid = tid >> 6;
  const int l15 = lane & 15, lg = lane >> 4;
  const int gw = blockIdx.x * 4 + wid;  // 0..1023

  short8 Wf[8][4];
  f32x4 biasD[8];
#pragma unroll
  for (int m = 0; m < 8; ++m) {
#pragma unroll
    for (int kt = 0; kt < 4; ++kt)
      Wf[m][kt] = load_row8_bf16(W_ih + (16 * m + l15) * Hd + 32 * kt + 8 * lg);
    const float4 bi = *reinterpret_cast<const float4*>(b_ih + 16 * m + 4 * lg);
    const float4 bh = *reinterpret_cast<const float4*>(b_hh + 16 * m + 4 * lg);
    biasD[m] = (f32x4){bi.x + bh.x, bi.y + bh.y, bi.z + bh.z, bi.w + bh.w};
  }

  for (int tt = gw; tt < 1875; tt += 1024) {
    const int v = tt * 16 + l15;
    short8 Ef[4];
#pragma unroll
    for (int kt = 0; kt < 4; ++kt)
      Ef[kt] = load_row8_bf16(embed + (size_t)v * Hd + 32 * kt + 8 * lg);
    f32x4 acc[8];
#pragma unroll
    for (int m = 0; m < 8; ++m) acc[m] = biasD[m];
#pragma unroll
    for (int kt = 0; kt < 4; ++kt)
#pragma unroll
      for (int m = 0; m < 8; ++m) acc[m] = mfma16(Wf[m][kt], Ef[kt], acc[m]);
    unsigned int dw[16];
#pragma unroll
    for (int m = 0; m < 8; ++m) {
      dw[2 * m]     = pack2(acc[m][0], acc[m][1]);
      dw[2 * m + 1] = pack2(acc[m][2], acc[m][3]);
    }
    unsigned int* dst = T1p + (size_t)v * 64 + lg * 16;
#pragma unroll
    for (int j = 0; j < 4; ++j)
      *reinterpret_cast<u32x4*>(dst + 4 * j) =
          (u32x4){dw[4 * j], dw[4 * j + 1], dw[4 * j + 2], dw[4 * j + 3]};
  }
}

// ---------------------------------------------------------------------------
// K2: skewed fused RNN. 512 blocks x 256 thr (4 waves). Wave ws owns output
// dims [32ws,32ws+32); 32 seqs/block (bt=0,1: s = bt*16 + l15).
// slab[buf][state]: per state 2bt x 16 rows(seq) x 256B;
//   byte = bt*4096 + row*256 + ((2h) ^ ((row&15)<<4)).
// ---------------------------------------------------------------------------
__global__ __launch_bounds__(256, 2) void k_rnn(
    const int* __restrict__ x, const unsigned int* __restrict__ T1p,
    const float* __restrict__ W_ih, const float* __restrict__ W_hh,
    const float* __restrict__ b_ih, const float* __restrict__ b_hh,
    const float* __restrict__ pred_W, float* __restrict__ sbuf) {
  __shared__ alignas(16) unsigned char slab[2][2][8192];  // [buf][state]
  __shared__ int xs[32 * 33 + 16];
  __shared__ float sred[4][32][2];

  const int tid = threadIdx.x, lane = tid & 63, ws = tid >> 6;
  const int l15 = lane & 15, lg = lane >> 4;
  const int seq0 = blockIdx.x * 32;

  // stage xs: xs[s][t] at s*33+t (1024 ints)
#pragma unroll
  for (int k = 0; k < 4; ++k) {
    int e = tid + k * 256;  // e = s*32 + t
    xs[(e >> 5) * 33 + (e & 31)] = x[(size_t)seq0 * Sd + e];
  }
  __syncthreads();

  const int s0 = l15, s1 = l15 + 16;   // local seqs (bt=0,1)
  const int jbase = 16 * lg + 4 * ws;  // T1p uint col for h=32ws+16mt+4lg+..

  // t1 gathers: t1c = current step's value, t1n = next (distance-2 prefetch)
  u32x2 t1c[2][2], t1n[2][2];
  {
    int i0 = xs[s0 * 33 + 0], i1 = xs[s1 * 33 + 0];
    const u32x2* p0 = reinterpret_cast<const u32x2*>(T1p + (size_t)i0 * 64 + jbase);
    const u32x2* p1 = reinterpret_cast<const u32x2*>(T1p + (size_t)i1 * 64 + jbase);
    t1c[0][0] = p0[0]; t1c[0][1] = p0[1];
    t1c[1][0] = p1[0]; t1c[1][1] = p1[1];
  }

  // weights (A-frags: row = h_out within tile = l15, k-slice = 32kt+8lg)
  short8 Wh0[2][4], Wi1[2][4], Wh1[2][4];
#pragma unroll
  for (int mt = 0; mt < 2; ++mt)
#pragma unroll
    for (int kt = 0; kt < 4; ++kt) {
      const int ro = (32 * ws + 16 * mt + l15) * Hd + 32 * kt + 8 * lg;
      Wh0[mt][kt] = load_row8_bf16(W_hh + ro);
      Wi1[mt][kt] = load_row8_bf16(W_ih + 16384 + ro);
      Wh1[mt][kt] = load_row8_bf16(W_hh + 16384 + ro);
    }
  // layer-1 bias, packed bf16 in D-pattern (h = 32ws+16mt+4lg+r)
  u32x2 bsumP[2];
#pragma unroll
  for (int mt = 0; mt < 2; ++mt) {
    const float4 bi = *reinterpret_cast<const float4*>(b_ih + Hd + 32 * ws + 16 * mt + 4 * lg);
    const float4 bh = *reinterpret_cast<const float4*>(b_hh + Hd + 32 * ws + 16 * mt + 4 * lg);
    bsumP[mt][0] = pack2(bi.x + bh.x, bi.y + bh.y);
    bsumP[mt][1] = pack2(bi.z + bh.z, bi.w + bh.w);
  }
  // slab offsets within a [state] buffer (loop-invariant)
  int wb[2][2], rb[2][4];
#pragma unroll
  for (int bt = 0; bt < 2; ++bt) {
#pragma unroll
    for (int mt = 0; mt < 2; ++mt)
      wb[bt][mt] = bt * 4096 + l15 * 256 + ((64 * ws + 32 * mt + 8 * lg) ^ (l15 << 4));
#pragma unroll
    for (int kt = 0; kt < 4; ++kt)
      rb[bt][kt] = bt * 4096 + l15 * 256 + ((64 * kt + 16 * lg) ^ (l15 << 4));
  }

  short8 h1f[2][4], h2f[2][4];
  f32x4 acc[2][2];  // [mt][bt]

  // ---- init phase: h1_0 = relu(t1_0); h2_{-1} = 0  -> buf 0
#pragma unroll
  for (int bt = 0; bt < 2; ++bt)
#pragma unroll
    for (int mt = 0; mt < 2; ++mt) {
      u32x2 q = t1c[bt][mt];
      u32x2 w;
      w[0] = pack2(fmaxf(blo(q[0]), 0.f), fmaxf(bhi(q[0]), 0.f));
      w[1] = pack2(fmaxf(blo(q[1]), 0.f), fmaxf(bhi(q[1]), 0.f));
      *reinterpret_cast<u32x2*>(&slab[0][0][0] + wb[bt][mt]) = w;
      *reinterpret_cast<u32x2*>(&slab[0][1][0] + wb[bt][mt]) = (u32x2){0u, 0u};
    }
  // load t1(1) into t1c, t1(2) into t1n (both in flight across the barrier)
  {
    int i0 = xs[s0 * 33 + 1], i1 = xs[s1 * 33 + 1];
    const u32x2* p0 = reinterpret_cast<const u32x2*>(T1p + (size_t)i0 * 64 + jbase);
    const u32x2* p1 = reinterpret_cast<const u32x2*>(T1p + (size_t)i1 * 64 + jbase);
    t1c[0][0] = p0[0]; t1c[0][1] = p0[1];
    t1c[1][0] = p1[0]; t1c[1][1] = p1[1];
    int j0 = xs[s0 * 33 + 2], j1 = xs[s1 * 33 + 2];
    const u32x2* q0 = reinterpret_cast<const u32x2*>(T1p + (size_t)j0 * 64 + jbase);
    const u32x2* q1 = reinterpret_cast<const u32x2*>(T1p + (size_t)j1 * 64 + jbase);
    t1n[0][0] = q0[0]; t1n[0][1] = q0[1];
    t1n[1][0] = q1[0]; t1n[1][1] = q1[1];
  }
  phase_fence();
#pragma unroll
  for (int bt = 0; bt < 2; ++bt)
#pragma unroll
    for (int kt = 0; kt < 4; ++kt) {
      h1f[bt][kt] = *reinterpret_cast<const short8*>(&slab[0][0][0] + rb[bt][kt]);
      h2f[bt][kt] = *reinterpret_cast<const short8*>(&slab[0][1][0] + rb[bt][kt]);
    }

  // ---- skewed steps t = 1..31: one barrier each.
  // entry: h1f = h1_{t-1}, h2f = h2_{t-2}, t1c = t1(t), t1n = t1(t+1)
#pragma unroll 1
  for (int t = 1; t < Sd; ++t) {
    const int pn = t & 1;  // write buffer this phase (read = pn^1)
    unsigned char* w1s = &slab[pn][0][0];
    unsigned char* w2s = &slab[pn][1][0];

    // h1_t = relu(Wh0·h1_{t-1} + t1_t)
#pragma unroll
    for (int mt = 0; mt < 2; ++mt)
#pragma unroll
      for (int bt = 0; bt < 2; ++bt)
        acc[mt][bt] = mfma16(Wh0[mt][0], h1f[bt][0], (f32x4){0.f, 0.f, 0.f, 0.f});
#pragma unroll
    for (int kt = 1; kt < 4; ++kt)
#pragma unroll
      for (int mt = 0; mt < 2; ++mt)
#pragma unroll
        for (int bt = 0; bt < 2; ++bt)
          acc[mt][bt] = mfma16(Wh0[mt][kt], h1f[bt][kt], acc[mt][bt]);
#pragma unroll
    for (int bt = 0; bt < 2; ++bt)
#pragma unroll
      for (int mt = 0; mt < 2; ++mt) {
        u32x2 q = t1c[bt][mt];
        f32x4 a = acc[mt][bt];
        u32x2 w;
        w[0] = pack2(fmaxf(a[0] + blo(q[0]), 0.f), fmaxf(a[1] + bhi(q[0]), 0.f));
        w[1] = pack2(fmaxf(a[2] + blo(q[1]), 0.f), fmaxf(a[3] + bhi(q[1]), 0.f));
        *reinterpret_cast<u32x2*>(w1s + wb[bt][mt]) = w;
      }
    // rotate prefetch: t1c <- t1n, issue t1n = t1(t+2) (2 phases of cover)
#pragma unroll
    for (int bt = 0; bt < 2; ++bt)
#pragma unroll
      for (int mt = 0; mt < 2; ++mt) t1c[bt][mt] = t1n[bt][mt];
    {
      const int tn = (t + 2 > 31) ? 31 : t + 2;
      int i0 = xs[s0 * 33 + tn], i1 = xs[s1 * 33 + tn];
      const u32x2* p0 = reinterpret_cast<const u32x2*>(T1p + (size_t)i0 * 64 + jbase);
      const u32x2* p1 = reinterpret_cast<const u32x2*>(T1p + (size_t)i1 * 64 + jbase);
      t1n[0][0] = p0[0]; t1n[0][1] = p0[1];
      t1n[1][0] = p1[0]; t1n[1][1] = p1[1];
    }

    // h2_{t-1} = relu(bsum + Wi1·h1_{t-1} + Wh1·h2_{t-2})
#pragma unroll
    for (int mt = 0; mt < 2; ++mt)
#pragma unroll
      for (int bt = 0; bt < 2; ++bt)
        acc[mt][bt] = (f32x4){blo(bsumP[mt][0]), bhi(bsumP[mt][0]),
                              blo(bsumP[mt][1]), bhi(bsumP[mt][1])};
#pragma unroll
    for (int kt = 0; kt < 4; ++kt)
#pragma unroll
      for (int mt = 0; mt < 2; ++mt)
#pragma unroll
        for (int bt = 0; bt < 2; ++bt) {
          acc[mt][bt] = mfma16(Wi1[mt][kt], h1f[bt][kt], acc[mt][bt]);
          acc[mt][bt] = mfma16(Wh1[mt][kt], h2f[bt][kt], acc[mt][bt]);
        }
#pragma unroll
    for (int bt = 0; bt < 2; ++bt)
#pragma unroll
      for (int mt = 0; mt < 2; ++mt) {
        f32x4 a = acc[mt][bt];
        u32x2 w;
        w[0] = pack2(fmaxf(a[0], 0.f), fmaxf(a[1], 0.f));
        w[1] = pack2(fmaxf(a[2], 0.f), fmaxf(a[3], 0.f));
        *reinterpret_cast<u32x2*>(w2s + wb[bt][mt]) = w;
      }

    phase_fence();
#pragma unroll
    for (int bt = 0; bt < 2; ++bt)
#pragma unroll
      for (int kt = 0; kt < 4; ++kt) {
        h1f[bt][kt] = *reinterpret_cast<const short8*>(w1s + rb[bt][kt]);
        h2f[bt][kt] = *reinterpret_cast<const short8*>(w2s + rb[bt][kt]);
      }
  }

  // ---- final: h2_31 = bsum + Wi1·h1_31 + Wh1·h2_30 (pre-relu, in regs)
#pragma unroll
  for (int mt = 0; mt < 2; ++mt)
#pragma unroll
    for (int bt = 0; bt < 2; ++bt)
      acc[mt][bt] = (f32x4){blo(bsumP[mt][0]), bhi(bsumP[mt][0]),
                            blo(bsumP[mt][1]), bhi(bsumP[mt][1])};
#pragma unroll
  for (int kt = 0; kt < 4; ++kt)
#pragma unroll
    for (int mt = 0; mt < 2; ++mt)
#pragma unroll
      for (int bt = 0; bt < 2; ++bt) {
        acc[mt][bt] = mfma16(Wi1[mt][kt], h1f[bt][kt], acc[mt][bt]);
        acc[mt][bt] = mfma16(Wh1[mt][kt], h2f[bt][kt], acc[mt][bt]);
      }

  // ---- epilogue: s1/s2 dots, reduce over lg then ws
  float p1[2] = {0.f, 0.f}, p2[2] = {0.f, 0.f};
#pragma unroll
  for (int mt = 0; mt < 2; ++mt) {
    const float4 w1 = *reinterpret_cast<const float4*>(pred_W + 32 * ws + 16 * mt + 4 * lg);
    const float4 w2 = *reinterpret_cast<const float4*>(pred_W + Hd + 32 * ws + 16 * mt + 4 * lg);
#pragma unroll
    for (int bt = 0; bt < 2; ++bt) {
      f32x4 a = acc[mt][bt];
      float a0 = fmaxf(a[0], 0.f), a1 = fmaxf(a[1], 0.f);
      float a2 = fmaxf(a[2], 0.f), a3 = fmaxf(a[3], 0.f);
      p1[bt] += a0 * w1.x + a1 * w1.y + a2 * w1.z + a3 * w1.w;
      p2[bt] += a0 * w2.x + a1 * w2.y + a2 * w2.z + a3 * w2.w;
    }
  }
#pragma unroll
  for (int bt = 0; bt < 2; ++bt) {
    p1[bt] += __shfl_xor(p1[bt], 16); p1[bt] += __shfl_xor(p1[bt], 32);
    p2[bt] += __shfl_xor(p2[bt], 16); p2[bt] += __shfl_xor(p2[bt], 32);
  }
  if (lg == 0) {
#pragma unroll
    for (int bt = 0; bt < 2; ++bt) {
      sred[ws][bt * 16 + l15][0] = p1[bt];
      sred[ws][bt * 16 + l15][1] = p2[bt];
    }
  }
  __syncthreads();
  if (tid < 64) {
    int nl = tid >> 1, st = tid & 1;
    float v = sred[0][nl][st] + sred[1][nl][st] + sred[2][nl][st] + sred[3][nl][st];
    sbuf[st * 16384 + seq0 + nl] = v;
  }
}

// ---------------------------------------------------------------------------
// K3: out[b,r,c] = s1 + rowsum_c(s2) + colsum_r(s2) - 2*s2 + pred_b
// ---------------------------------------------------------------------------
__global__ __launch_bounds__(1024) void k_final(const float* __restrict__ sbuf,
                                                const float* __restrict__ pred_b,
                                                float* __restrict__ out) {
  __shared__ float s2s[64][65];
  __shared__ float rowS[64], colS[64];
  const int b = blockIdx.x, tid = threadIdx.x;
  const float* s1g = sbuf + b * 4096;
  const float* s2g = sbuf + 16384 + b * 4096;
#pragma unroll
  for (int i = 0; i < 4; ++i) {
    int j = tid + i * 1024;
    s2s[j >> 6][j & 63] = s2g[j];
  }
  __syncthreads();
  if (tid < 64) {
    float s = 0.f;
    for (int cc = 0; cc < 64; ++cc) s += s2s[tid][cc];
    rowS[tid] = s;
  } else if (tid < 128) {
    int cc = tid - 64;
    float s = 0.f;
    for (int r = 0; r < 64; ++r) s += s2s[r][cc];
    colS[cc] = s;
  }
  __syncthreads();
  const float pb = pred_b[0];
#pragma unroll
  for (int i = 0; i < 4; ++i) {
    int j = tid + i * 1024;
    int r = j >> 6, cc = j & 63;
    out[b * 4096 + j] = s1g[j] + rowS[r] + colS[cc] - 2.f * s2s[r][cc] + pb;
  }
}

// ---------------------------------------------------------------------------
extern "C" void kernel_launch(void* const* d_in, const int* in_sizes, int n_in,
                              void* d_out, int out_size, void* d_ws,
                              size_t ws_size, hipStream_t stream) {
  const int* x = (const int*)d_in[0];
  const float* embed = (const float*)d_in[1];
  const float* W_ih = (const float*)d_in[2];
  const float* W_hh = (const float*)d_in[3];
  const float* b_ih = (const float*)d_in[4];
  const float* b_hh = (const float*)d_in[5];
  const float* pred_W = (const float*)d_in[6];
  const float* pred_b = (const float*)d_in[7];

  // ws layout: T1p (7,680,000 B) | sbuf (131,072 B)
  unsigned int* T1p = (unsigned int*)d_ws;
  float* sbuf = (float*)((char*)d_ws + (size_t)VROWS * 256);
  float* out = (float*)d_out;

  k_t1p<<<256, 256, 0, stream>>>(embed, W_ih, b_ih, b_hh, T1p);
  k_rnn<<<512, 256, 0, stream>>>(x, T1p, W_ih, W_hh, b_ih, b_hh, pred_W, sbuf);
  k_final<<<4, 1024, 0, stream>>>(sbuf, pred_b, out);
}